// Round 10
// baseline (485.887 us; speedup 1.0000x reference)
//
#include <hip/hip_runtime.h>
#include <hip/hip_bf16.h>
#include <hip/hip_cooperative_groups.h>
#include <math.h>

namespace cg = cooperative_groups;

#define NN 2048
#define LOG2E 1.4426950408889634f

typedef __attribute__((ext_vector_type(8))) short short8;
typedef __attribute__((ext_vector_type(4))) short s16x4;
typedef __attribute__((ext_vector_type(4))) float f32x4;

__device__ inline unsigned short f2bfu(float f) {
    __hip_bfloat16 h = __float2bfloat16(f);
    return *reinterpret_cast<const unsigned short*>(&h);
}
__device__ inline short f2bfs(float f) {
    __hip_bfloat16 h = __float2bfloat16(f);
    return *reinterpret_cast<const short*>(&h);
}
__device__ inline float bfu2f(unsigned short u) {
    return __uint_as_float(((unsigned int)u) << 16);
}

// ================= prep sub-tasks (shared by mega-P0 and fallback prep_k) =========
__device__ __forceinline__ void adj_task(
    const int* __restrict__ adj, unsigned long long* __restrict__ adjm, int task, int l)
{
    const int row = task >> 5, ch = task & 31;
    const int v = adj[(size_t)row * NN + ch * 64 + l];
    const unsigned long long bm = __ballot(v != 0);
    if (l == 0) adjm[task] = bm;
}

__device__ __forceinline__ void xpack_task(
    const float* __restrict__ x, unsigned short* __restrict__ axH,
    unsigned short* __restrict__ axL, int f, int l)
{
    const int gq = l >> 4, n16 = l & 15;
    const int mt = f >> 4, kt = f & 15;
    const int row = mt * 16 + n16;
    const int k0 = kt * 32 + 4 * gq;
    unsigned short uh[8], ul[8];
    #pragma unroll
    for (int eh = 0; eh < 2; ++eh) {
        const float4 v4 = *(const float4*)&x[(size_t)row * 512 + k0 + 16 * eh];
        const float vv[4] = {v4.x, v4.y, v4.z, v4.w};
        #pragma unroll
        for (int c = 0; c < 4; ++c) {
            const float v = vv[c];
            const unsigned short hi = f2bfu(v);
            uh[4 * eh + c] = hi;
            ul[4 * eh + c] = f2bfu(v - bfu2f(hi));
        }
    }
    *(short8*)&axH[(size_t)f * 512 + l * 8] = *(const short8*)uh;
    *(short8*)&axL[(size_t)f * 512 + l * 8] = *(const short8*)ul;
}

__device__ __forceinline__ void wpack_task(
    const float* __restrict__ W1, unsigned short* __restrict__ w1H, unsigned short* __restrict__ w1L,
    const float* __restrict__ W2, unsigned short* __restrict__ w2H, unsigned short* __restrict__ w2L,
    int f0, int l)
{
    const int gq = l >> 4, n16 = l & 15;
    int f = f0;
    const float* B; unsigned short *bH, *bL; int N;
    if (f < 512) { B = W1; bH = w1H; bL = w1L; N = 512; }
    else         { B = W2; bH = w2H; bL = w2L; N = 256; f -= 512; }
    const int nt = f >> 4, kt = f & 15;
    const int col = nt * 16 + n16;
    unsigned short uh[8], ul[8];
    #pragma unroll
    for (int e = 0; e < 8; ++e) {
        const int k = kt * 32 + 4 * gq + (e & 3) + 16 * (e >> 2);
        const float v = B[(size_t)k * N + col];
        const unsigned short hi = f2bfu(v);
        uh[e] = hi;
        ul[e] = f2bfu(v - bfu2f(hi));
    }
    *(short8*)&bH[(size_t)f * 512 + l * 8] = *(const short8*)uh;
    *(short8*)&bL[(size_t)f * 512 + l * 8] = *(const short8*)ul;
}

// ================= per-wave split-bf16 GEMM + fused epilogue (R8-verbatim) =========
__device__ __forceinline__ void gemm_wave(
    const unsigned short* __restrict__ aH, const unsigned short* __restrict__ aL,
    const unsigned short* __restrict__ bH, const unsigned short* __restrict__ bL,
    const float* __restrict__ av, unsigned short* __restrict__ gpO,
    float* __restrict__ slO, float* __restrict__ srO,
    int dh, int NT, int mt, int cb, int l)
{
    const int gq = l >> 4, n16 = l & 15;
    const int nt0 = cb * 4;
    const size_t abase = (size_t)mt * 16 * 512 + l * 8;

    f32x4 acc[4];
    #pragma unroll
    for (int nt = 0; nt < 4; ++nt) acc[nt] = f32x4{0.f, 0.f, 0.f, 0.f};

#define GGL(aH_v, aL_v, bH_v, bL_v, kt_) do {                                    \
    const int kk_ = (kt_);                                                       \
    aH_v = *(const short8*)&aH[abase + (size_t)kk_ * 512];                       \
    aL_v = *(const short8*)&aL[abase + (size_t)kk_ * 512];                       \
    _Pragma("unroll")                                                            \
    for (int nt_ = 0; nt_ < 4; ++nt_) {                                          \
        const size_t bo_ = ((size_t)(nt0 + nt_) * 16 + kk_) * 512 + l * 8;       \
        bH_v[nt_] = *(const short8*)&bH[bo_];                                    \
        bL_v[nt_] = *(const short8*)&bL[bo_];                                    \
    }                                                                            \
} while (0)

#define GGC(aH_v, aL_v, bH_v, bL_v) do {                                         \
    _Pragma("unroll")                                                            \
    for (int nt_ = 0; nt_ < 4; ++nt_) {                                          \
        acc[nt_] = __builtin_amdgcn_mfma_f32_16x16x32_bf16(aH_v, bH_v[nt_], acc[nt_], 0, 0, 0); \
        acc[nt_] = __builtin_amdgcn_mfma_f32_16x16x32_bf16(aH_v, bL_v[nt_], acc[nt_], 0, 0, 0); \
        acc[nt_] = __builtin_amdgcn_mfma_f32_16x16x32_bf16(aL_v, bH_v[nt_], acc[nt_], 0, 0, 0); \
    }                                                                            \
} while (0)

    short8 aHa, aLa, bHa[4], bLa[4], aHb, aLb, bHb[4], bLb[4];
    GGL(aHa, aLa, bHa, bLa, 0);
    GGL(aHb, aLb, bHb, bLb, 1);
    for (int kt = 0; kt < 16; kt += 2) {
        GGC(aHa, aLa, bHa, bLa);
        if (kt + 2 < 16) GGL(aHa, aLa, bHa, bLa, kt + 2);
        GGC(aHb, aLb, bHb, bLb);
        if (kt + 3 < 16) GGL(aHb, aLb, bHb, bLb, kt + 3);
    }
#undef GGL
#undef GGC

    #pragma unroll
    for (int nt = 0; nt < 4; ++nt) {
        s16x4 u;
        #pragma unroll
        for (int c = 0; c < 4; ++c) u[c] = (short)f2bfu(acc[nt][c]);
        const int f = (mt >> 1) * NT + (nt0 + nt);
        *(s16x4*)&gpO[(size_t)f * 512 + l * 8 + 4 * (mt & 1)] = u;
    }
    const float* al = av;
    const float* ar = av + dh;
    float pl[4] = {0.f, 0.f, 0.f, 0.f}, pr[4] = {0.f, 0.f, 0.f, 0.f};
    #pragma unroll
    for (int nt = 0; nt < 4; ++nt) {
        const int q = (cb * 64 + 16 * nt + n16) & (dh - 1);
        const float wl = al[q], wr_ = ar[q];
        #pragma unroll
        for (int r = 0; r < 4; ++r) { pl[r] += acc[nt][r] * wl; pr[r] += acc[nt][r] * wr_; }
    }
    #pragma unroll
    for (int r = 0; r < 4; ++r) {
        #pragma unroll
        for (int off = 1; off < 16; off <<= 1) {
            pl[r] += __shfl_xor(pl[r], off);
            pr[r] += __shfl_xor(pr[r], off);
        }
    }
    if (n16 == 0) {
        const int hbase = (dh == 64 ? cb : 0) * NN;
        #pragma unroll
        for (int r = 0; r < 4; ++r) {
            const int grow = 16 * mt + 4 * gq + r;
            atomicAdd(&slO[hbase + grow], pl[r] * LOG2E);
            atomicAdd(&srO[hbase + grow], pr[r] * LOG2E);
        }
    }
}

// ================= attention task (R8 attn_mfma6 verbatim, parameterized) ==========
template<int MT, int OUTMODE>
__device__ __forceinline__ void attn_task(
    const float* __restrict__ slv, const float* __restrict__ srv,
    const unsigned short* __restrict__ gp, const unsigned int* __restrict__ adjm32,
    float* __restrict__ out, unsigned short* __restrict__ aoH, unsigned short* __restrict__ aoL,
    int out_cols, int h, int do_elu, int ntg_total, int ib, int cb,
    float* accs_raw, float* zpf, int t)
{
    const int w = t >> 6, l = t & 63;
    const int gq = l >> 4, n16 = l & 15;
    const int i0 = ib * (MT * 16);
    const int ntg0 = cb * 4;
    const float* srh = srv + (size_t)h * NN;
    int arow[MT];
    float slr[MT];
    #pragma unroll
    for (int mt = 0; mt < MT; ++mt) {
        arow[mt] = i0 + 16 * mt + n16;
        slr[mt] = slv[(size_t)h * NN + arow[mt]];
    }

    f32x4 acc[MT][4];
    float zacc[MT];
    #pragma unroll
    for (int mt = 0; mt < MT; ++mt) {
        zacc[mt] = 0.f;
        #pragma unroll
        for (int nt = 0; nt < 4; ++nt) acc[mt][nt] = f32x4{0.f, 0.f, 0.f, 0.f};
    }

#define LOADH(bf_, sr_, am_, tile_, s_) do {                                     \
    const int tl_ = (tile_);                                                     \
    _Pragma("unroll")                                                            \
    for (int nt_ = 0; nt_ < 4; ++nt_)                                            \
        bf_[nt_] = *(const short8*)&gp[                                          \
            (size_t)((2 * tl_ + (s_)) * ntg_total + ntg0 + nt_) * 512 + l * 8];  \
    _Pragma("unroll")                                                            \
    for (int hb_ = 0; hb_ < 2; ++hb_)                                            \
        sr_[hb_] = *(const f32x4*)&srh[64 * tl_ + 32 * (s_) + 16 * hb_ + 4 * gq];\
    _Pragma("unroll")                                                            \
    for (int mt_ = 0; mt_ < MT; ++mt_)                                           \
        am_[mt_] = adjm32[((size_t)arow[mt_] * 32 + tl_) * 2 + (s_)];            \
} while (0)

#define COMPH(bf_, sr_, am_) do {                                                \
    short8 af_[MT];                                                              \
    _Pragma("unroll")                                                            \
    for (int mt_ = 0; mt_ < MT; ++mt_) {                                         \
        const unsigned am32_ = am_[mt_] >> (4 * gq);                             \
        _Pragma("unroll")                                                        \
        for (int hb_ = 0; hb_ < 2; ++hb_) {                                      \
            const f32x4 s4_ = sr_[hb_];                                          \
            _Pragma("unroll")                                                    \
            for (int c_ = 0; c_ < 4; ++c_) {                                     \
                float f_ = slr[mt_] + s4_[c_];                                   \
                f_ = fmaxf(f_, 0.2f * f_);                                       \
                float wv_ = __builtin_amdgcn_exp2f(f_);                          \
                const int msk_ = (int)(am32_ << (31 - (c_ + 16 * hb_))) >> 31;   \
                wv_ = __int_as_float(__float_as_int(wv_) & msk_);                \
                zacc[mt_] += wv_;                                                \
                af_[mt_][4 * hb_ + c_] = f2bfs(wv_);                             \
            }                                                                    \
        }                                                                        \
    }                                                                            \
    _Pragma("unroll")                                                            \
    for (int mt_ = 0; mt_ < MT; ++mt_)                                           \
        _Pragma("unroll")                                                        \
        for (int nt_ = 0; nt_ < 4; ++nt_)                                        \
            acc[mt_][nt_] = __builtin_amdgcn_mfma_f32_16x16x32_bf16(             \
                af_[mt_], bf_[nt_], acc[mt_][nt_], 0, 0, 0);                     \
} while (0)

    unsigned amA[MT], amB[MT];
    f32x4 srA[2], srB[2];
    short8 bfA[4], bfB[4];

    LOADH(bfA, srA, amA, w, 0);
    LOADH(bfB, srB, amB, w, 1);
    #pragma unroll
    for (int k = 0; k < 4; ++k) {
        const int tn = (k < 3) ? (w + 8 * (k + 1)) : (w + 8 * k);   // guarded prefetch
        COMPH(bfA, srA, amA);
        LOADH(bfA, srA, amA, tn, 0);
        COMPH(bfB, srB, amB);
        LOADH(bfB, srB, amB, tn, 1);
    }
#undef LOADH
#undef COMPH

    #pragma unroll
    for (int mt = 0; mt < MT; ++mt) {
        zacc[mt] += __shfl_xor(zacc[mt], 16);
        zacc[mt] += __shfl_xor(zacc[mt], 32);
    }
    if (l < 16) {
        #pragma unroll
        for (int mt = 0; mt < MT; ++mt) zpf[w * (MT * 16) + 16 * mt + l] = zacc[mt];
    }

    if constexpr (OUTMODE == 0) {
        #pragma unroll
        for (int nt = 0; nt < 4; ++nt)
            #pragma unroll
            for (int r = 0; r < 4; ++r)
                accs_raw[((w * 4 + nt) * 4 + r) * 65 + l] = acc[0][nt][r];
        __syncthreads();
        #pragma unroll
        for (int idx = 0; idx < 2; ++idx) {
            const int flat = w + 8 * idx;            // 0..15
            const int nt = flat >> 2, r = flat & 3;
            const int ro = 4 * gq + r;
            float z = 0.f, v = 0.f;
            #pragma unroll
            for (int jj = 0; jj < 8; ++jj) {
                z += zpf[jj * 16 + ro];
                v += accs_raw[((jj * 4 + nt) * 4 + r) * 65 + l];
            }
            float o = v / z;
            if (do_elu) o = (o > 0.f) ? o : (__builtin_amdgcn_exp2f(o * LOG2E) - 1.f);
            out[(size_t)(i0 + ro) * out_cols + cb * 64 + nt * 16 + n16] = o;
        }
        __syncthreads();   // protects accs_raw/zpf reuse across looped tasks
    } else {
        const int mtl = w & 1, eh = (w >> 1) & 1;
        const int rowl = l & 15, colq = l >> 4;
        #pragma unroll
        for (int h2 = 0; h2 < 2; ++h2) {
            #pragma unroll
            for (int mt = 0; mt < MT; ++mt)
                #pragma unroll
                for (int ntl = 0; ntl < 2; ++ntl)
                    #pragma unroll
                    for (int r = 0; r < 4; ++r)
                        accs_raw[(((w * 2 + mt) * 2 + ntl) * 4 + r) * 65 + l] =
                            acc[mt][2 * h2 + ntl][r];
            __syncthreads();
            if (w < 4) {
                const int grow = 16 * mtl + rowl;
                float z = 0.f;
                #pragma unroll
                for (int jj = 0; jj < 8; ++jj) z += zpf[jj * 32 + grow];
                const float rz = 1.0f / z;
                unsigned short uh[4], ul[4];
                #pragma unroll
                for (int c = 0; c < 4; ++c) {
                    const int c16 = 4 * colq + c;
                    float v = 0.f;
                    #pragma unroll
                    for (int jj = 0; jj < 8; ++jj)
                        v += accs_raw[(((jj * 2 + mtl) * 2 + eh) * 4 + (rowl & 3)) * 65
                                      + (rowl >> 2) * 16 + c16];
                    float o = v * rz;
                    o = (o > 0.f) ? o : (__builtin_amdgcn_exp2f(o * LOG2E) - 1.f);  // ELU
                    const unsigned short hi = f2bfu(o);
                    uh[c] = hi;
                    ul[c] = f2bfu(o - bfu2f(hi));
                }
                const int mtg = ib * 2 + mtl;
                const int kt = 2 * cb + h2;
                const size_t off = ((size_t)mtg * 16 + kt) * 512 + l * 8 + 4 * eh;
                *(s16x4*)&aoH[off] = *(const s16x4*)uh;
                *(s16x4*)&aoL[off] = *(const s16x4*)ul;
            }
            __syncthreads();
        }
    }
}

// ================= fallback standalone kernels (R8 pipeline) =======================
__global__ __launch_bounds__(256) void prep_k(
    const int* __restrict__ adj, unsigned long long* __restrict__ adjm,
    float* __restrict__ zeros,
    const float* __restrict__ W1, unsigned short* __restrict__ w1H, unsigned short* __restrict__ w1L,
    const float* __restrict__ W2, unsigned short* __restrict__ w2H, unsigned short* __restrict__ w2L,
    const float* __restrict__ x, unsigned short* __restrict__ axH, unsigned short* __restrict__ axL)
{
    const int b = blockIdx.x, t = threadIdx.x, w = t >> 6, l = t & 63;
    adj_task(adj, adjm, b * 4 + w, l);
    if (b < 144) zeros[b * 256 + t] = 0.f;
    else if (b >= 256 && b < 448) wpack_task(W1, w1H, w1L, W2, w2H, w2L, (b - 256) * 4 + w, l);
    else if (b >= 448 && b < 960) xpack_task(x, axH, axL, (b - 448) * 4 + w, l);
}

__global__ __launch_bounds__(256, 2) void gemm_k(
    const unsigned short* __restrict__ aH, const unsigned short* __restrict__ aL,
    const unsigned short* __restrict__ bH, const unsigned short* __restrict__ bL,
    const float* __restrict__ av, unsigned short* __restrict__ gpO,
    float* __restrict__ slO, float* __restrict__ srO, int dh, int NT)
{
    const int t = threadIdx.x, w = t >> 6, l = t & 63;
    gemm_wave(aH, aL, bH, bL, av, gpO, slO, srO, dh, NT, blockIdx.x * 4 + w, blockIdx.y, l);
}

template<int MT, int OUTMODE>
__global__ __launch_bounds__(512, 4) void attn_k(
    const float* __restrict__ slv, const float* __restrict__ srv,
    const unsigned short* __restrict__ gp, const unsigned int* __restrict__ adjm32,
    float* __restrict__ out, unsigned short* __restrict__ aoH, unsigned short* __restrict__ aoL,
    int out_cols, int hsel, int do_elu, int ntg_total)
{
    __shared__ float accs_raw[8320];
    __shared__ float zpf[256];
    const int cb = blockIdx.y;
    const int h = (hsel < 0) ? cb : hsel;
    attn_task<MT, OUTMODE>(slv, srv, gp, adjm32, out, aoH, aoL, out_cols, h, do_elu,
                           ntg_total, blockIdx.x, cb, accs_raw, zpf, threadIdx.x);
}

// ================= cooperative mega kernel (gridDim-stride task loops) =============
__global__ __launch_bounds__(512, 4) void mega(
    const float* __restrict__ x, const int* __restrict__ adj,
    const float* __restrict__ W1, const float* __restrict__ a1,
    const float* __restrict__ W2, const float* __restrict__ a2,
    float* __restrict__ out, unsigned char* __restrict__ ws)
{
    float* sl1 = (float*)ws;                    // 8*2048
    float* sr1 = sl1 + 8 * 2048;
    float* sl2 = sr1 + 8 * 2048;                // 2048
    float* sr2 = sl2 + 2048;
    unsigned long long* adjm = (unsigned long long*)(sr2 + 2048);   // 65536 u64
    unsigned short* gp1 = (unsigned short*)(adjm + 65536);          // 2048 frags
    unsigned short* gp2 = gp1 + 2048 * 512;     // 1024 frags
    unsigned short* axH = gp2 + 1024 * 512;
    unsigned short* axL = axH + 2048 * 512;
    unsigned short* ahH = axL + 2048 * 512;
    unsigned short* ahL = ahH + 2048 * 512;
    unsigned short* w1H = ahL + 2048 * 512;
    unsigned short* w1L = w1H + 512 * 512;
    unsigned short* w2H = w1L + 512 * 512;
    unsigned short* w2L = w2H + 256 * 512;

    __shared__ float accs_raw[8320];
    __shared__ float zpf[256];

    const int b = blockIdx.x, NB = gridDim.x, t = threadIdx.x;
    const int w8 = t >> 6, l = t & 63;
    const int gw8 = b * 8 + w8;
    const int TW = NB * 8;
    cg::grid_group grid = cg::this_grid();

    // ===== P0: prep =====
    for (int g = b * 512 + t; g < 36864; g += NB * 512) sl1[g] = 0.f;
    for (int task = gw8; task < 65536; task += TW) adj_task(adj, adjm, task, l);
    for (int f = gw8; f < 2048; f += TW) xpack_task(x, axH, axL, f, l);
    for (int f = gw8; f < 768; f += TW) wpack_task(W1, w1H, w1L, W2, w2H, w2L, f, l);
    __threadfence();
    grid.sync();

    // ===== P1: gemm1 (1024 wave-tasks) =====
    for (int task = b + NB * w8; task < 1024; task += TW)
        gemm_wave(axH, axL, w1H, w1L, a1, gp1, sl1, sr1, 64, 32, task >> 3, task & 7, l);
    __threadfence();
    grid.sync();

    // ===== P2: attn1 (512 block-tasks; MT=2, emit A-frags, ELU) =====
    for (int task = b; task < 512; task += NB)
        attn_task<2, 1>(sl1, sr1, gp1, (const unsigned int*)adjm,
                        nullptr, ahH, ahL, 512, task & 7, 1, 32, task >> 3, task & 7,
                        accs_raw, zpf, t);
    __threadfence();
    grid.sync();

    // ===== P3: gemm2 (512 wave-tasks) =====
    for (int task = b + NB * w8; task < 512; task += TW)
        gemm_wave(ahH, ahL, w2H, w2L, a2, gp2, sl2, sr2, 256, 16, task >> 2, task & 3, l);
    __threadfence();
    grid.sync();

    // ===== P4: attn2 (512 block-tasks; MT=1, fp32 out) =====
    for (int task = b; task < 512; task += NB)
        attn_task<1, 0>(sl2, sr2, gp2, (const unsigned int*)adjm,
                        out, nullptr, nullptr, 256, 0, 0, 16, task >> 2, task & 3,
                        accs_raw, zpf, t);
}

extern "C" void kernel_launch(void* const* d_in, const int* in_sizes, int n_in,
                              void* d_out, int out_size, void* d_ws, size_t ws_size,
                              hipStream_t stream)
{
    const float* x   = (const float*)d_in[0];   // 2048 x 512
    const int*   adj = (const int*)  d_in[1];   // 2048 x 2048
    const float* W1  = (const float*)d_in[2];   // 512 x 512
    const float* a1  = (const float*)d_in[3];   // 128
    const float* W2  = (const float*)d_in[4];   // 512 x 256
    const float* a2  = (const float*)d_in[5];   // 512
    float* outp = (float*)d_out;                // 2048 x 256
    unsigned char* wsb = (unsigned char*)d_ws;

    // ---- workspace layout (shared by both paths) ----
    float* sl1 = (float*)d_ws;
    float* sr1 = sl1 + 8 * 2048;
    float* sl2 = sr1 + 8 * 2048;
    float* sr2 = sl2 + 2048;
    unsigned long long* adjm = (unsigned long long*)(sr2 + 2048);
    unsigned short* gp1 = (unsigned short*)(adjm + 65536);
    unsigned short* gp2 = gp1 + 2048 * 512;
    unsigned short* axH = gp2 + 1024 * 512;
    unsigned short* axL = axH + 2048 * 512;
    unsigned short* ahH = axL + 2048 * 512;
    unsigned short* ahL = ahH + 2048 * 512;
    unsigned short* w1H = ahL + 2048 * 512;
    unsigned short* w1L = w1H + 512 * 512;
    unsigned short* w2H = w1L + 512 * 512;
    unsigned short* w2L = w2H + 256 * 512;

    // ---- try the cooperative mega-kernel with occupancy-adapted grid ----
    bool launched = false;
    int dev = 0;
    if (hipGetDevice(&dev) == hipSuccess) {
        int coop = 0;
        (void)hipDeviceGetAttribute(&coop, hipDeviceAttributeCooperativeLaunch, dev);
        int maxb = 0;
        if (coop &&
            hipOccupancyMaxActiveBlocksPerMultiprocessor(
                &maxb, (const void*)mega, 512, 0) == hipSuccess &&
            maxb > 0) {
            int NB = maxb * 256;
            if (NB > 512) NB = 512;
            void* args[] = {(void*)&x, (void*)&adj, (void*)&W1, (void*)&a1,
                            (void*)&W2, (void*)&a2, (void*)&outp, (void*)&wsb};
            launched = hipLaunchCooperativeKernel(reinterpret_cast<const void*>(&mega),
                                                  dim3((unsigned)NB), dim3(512),
                                                  args, 0, stream) == hipSuccess;
        }
    }

    // ---- fallback: proven R8 5-kernel pipeline ----
    if (!launched) {
        prep_k<<<dim3(16384), 256, 0, stream>>>(adj, adjm, sl1,
                                                W1, w1H, w1L, W2, w2H, w2L, x, axH, axL);
        gemm_k<<<dim3(32, 8), 256, 0, stream>>>(axH, axL, w1H, w1L, a1, gp1, sl1, sr1, 64, 32);
        attn_k<2, 1><<<dim3(64, 8), 512, 0, stream>>>(sl1, sr1, gp1, (const unsigned int*)adjm,
                                                      nullptr, ahH, ahL, 512, -1, 1, 32);
        gemm_k<<<dim3(32, 4), 256, 0, stream>>>(ahH, ahL, w2H, w2L, a2, gp2, sl2, sr2, 256, 16);
        attn_k<1, 0><<<dim3(128, 4), 512, 0, stream>>>(sl2, sr2, gp2, (const unsigned int*)adjm,
                                                       outp, nullptr, nullptr, 256, 0, 0, 16);
    }
}

// Round 11
// 70.621 us; speedup vs baseline: 6.8802x; 6.8802x over previous
//
#include <hip/hip_runtime.h>
#include <hip/hip_bf16.h>
#include <math.h>

#define NN 2048
#define LOG2E 1.4426950408889634f

typedef __attribute__((ext_vector_type(8))) short short8;
typedef __attribute__((ext_vector_type(4))) short s16x4;
typedef __attribute__((ext_vector_type(4))) float f32x4;

__device__ inline unsigned short f2bfu(float f) {
    __hip_bfloat16 h = __float2bfloat16(f);
    return *reinterpret_cast<const unsigned short*>(&h);
}
__device__ inline short f2bfs(float f) {
    __hip_bfloat16 h = __float2bfloat16(f);
    return *reinterpret_cast<const short*>(&h);
}
__device__ inline float bfu2f(unsigned short u) {
    return __uint_as_float(((unsigned int)u) << 16);
}

// ================= prep sub-tasks ==================================================
__device__ __forceinline__ void adj_task(
    const int* __restrict__ adj, unsigned long long* __restrict__ adjm, int task, int l)
{
    const int row = task >> 5, ch = task & 31;
    const int v = adj[(size_t)row * NN + ch * 64 + l];
    const unsigned long long bm = __ballot(v != 0);
    if (l == 0) adjm[task] = bm;
}

__device__ __forceinline__ void xpack_task(
    const float* __restrict__ x, unsigned short* __restrict__ axH,
    unsigned short* __restrict__ axL, int f, int l)
{
    const int gq = l >> 4, n16 = l & 15;
    const int mt = f >> 4, kt = f & 15;
    const int row = mt * 16 + n16;
    const int k0 = kt * 32 + 4 * gq;
    unsigned short uh[8], ul[8];
    #pragma unroll
    for (int eh = 0; eh < 2; ++eh) {
        const float4 v4 = *(const float4*)&x[(size_t)row * 512 + k0 + 16 * eh];
        const float vv[4] = {v4.x, v4.y, v4.z, v4.w};
        #pragma unroll
        for (int c = 0; c < 4; ++c) {
            const float v = vv[c];
            const unsigned short hi = f2bfu(v);
            uh[4 * eh + c] = hi;
            ul[4 * eh + c] = f2bfu(v - bfu2f(hi));
        }
    }
    *(short8*)&axH[(size_t)f * 512 + l * 8] = *(const short8*)uh;
    *(short8*)&axL[(size_t)f * 512 + l * 8] = *(const short8*)ul;
}

__device__ __forceinline__ void wpack_task(
    const float* __restrict__ W1, unsigned short* __restrict__ w1H, unsigned short* __restrict__ w1L,
    const float* __restrict__ W2, unsigned short* __restrict__ w2H, unsigned short* __restrict__ w2L,
    int f0, int l)
{
    const int gq = l >> 4, n16 = l & 15;
    int f = f0;
    const float* B; unsigned short *bH, *bL; int N;
    if (f < 512) { B = W1; bH = w1H; bL = w1L; N = 512; }
    else         { B = W2; bH = w2H; bL = w2L; N = 256; f -= 512; }
    const int nt = f >> 4, kt = f & 15;
    const int col = nt * 16 + n16;
    unsigned short uh[8], ul[8];
    #pragma unroll
    for (int e = 0; e < 8; ++e) {
        const int k = kt * 32 + 4 * gq + (e & 3) + 16 * (e >> 2);
        const float v = B[(size_t)k * N + col];
        const unsigned short hi = f2bfu(v);
        uh[e] = hi;
        ul[e] = f2bfu(v - bfu2f(hi));
    }
    *(short8*)&bH[(size_t)f * 512 + l * 8] = *(const short8*)uh;
    *(short8*)&bL[(size_t)f * 512 + l * 8] = *(const short8*)ul;
}

// ================= per-wave split-bf16 GEMM + fused epilogue =======================
__device__ __forceinline__ void gemm_wave(
    const unsigned short* __restrict__ aH, const unsigned short* __restrict__ aL,
    const unsigned short* __restrict__ bH, const unsigned short* __restrict__ bL,
    const float* __restrict__ av, unsigned short* __restrict__ gpO,
    float* __restrict__ slO, float* __restrict__ srO,
    int dh, int NT, int mt, int cb, int l)
{
    const int gq = l >> 4, n16 = l & 15;
    const int nt0 = cb * 4;
    const size_t abase = (size_t)mt * 16 * 512 + l * 8;

    f32x4 acc[4];
    #pragma unroll
    for (int nt = 0; nt < 4; ++nt) acc[nt] = f32x4{0.f, 0.f, 0.f, 0.f};

#define GGL(aH_v, aL_v, bH_v, bL_v, kt_) do {                                    \
    const int kk_ = (kt_);                                                       \
    aH_v = *(const short8*)&aH[abase + (size_t)kk_ * 512];                       \
    aL_v = *(const short8*)&aL[abase + (size_t)kk_ * 512];                       \
    _Pragma("unroll")                                                            \
    for (int nt_ = 0; nt_ < 4; ++nt_) {                                          \
        const size_t bo_ = ((size_t)(nt0 + nt_) * 16 + kk_) * 512 + l * 8;       \
        bH_v[nt_] = *(const short8*)&bH[bo_];                                    \
        bL_v[nt_] = *(const short8*)&bL[bo_];                                    \
    }                                                                            \
} while (0)

#define GGC(aH_v, aL_v, bH_v, bL_v) do {                                         \
    _Pragma("unroll")                                                            \
    for (int nt_ = 0; nt_ < 4; ++nt_) {                                          \
        acc[nt_] = __builtin_amdgcn_mfma_f32_16x16x32_bf16(aH_v, bH_v[nt_], acc[nt_], 0, 0, 0); \
        acc[nt_] = __builtin_amdgcn_mfma_f32_16x16x32_bf16(aH_v, bL_v[nt_], acc[nt_], 0, 0, 0); \
        acc[nt_] = __builtin_amdgcn_mfma_f32_16x16x32_bf16(aL_v, bH_v[nt_], acc[nt_], 0, 0, 0); \
    }                                                                            \
} while (0)

    short8 aHa, aLa, bHa[4], bLa[4], aHb, aLb, bHb[4], bLb[4];
    GGL(aHa, aLa, bHa, bLa, 0);
    GGL(aHb, aLb, bHb, bLb, 1);
    for (int kt = 0; kt < 16; kt += 2) {
        GGC(aHa, aLa, bHa, bLa);
        if (kt + 2 < 16) GGL(aHa, aLa, bHa, bLa, kt + 2);
        GGC(aHb, aLb, bHb, bLb);
        if (kt + 3 < 16) GGL(aHb, aLb, bHb, bLb, kt + 3);
    }
#undef GGL
#undef GGC

    #pragma unroll
    for (int nt = 0; nt < 4; ++nt) {
        s16x4 u;
        #pragma unroll
        for (int c = 0; c < 4; ++c) u[c] = (short)f2bfu(acc[nt][c]);
        const int f = (mt >> 1) * NT + (nt0 + nt);
        *(s16x4*)&gpO[(size_t)f * 512 + l * 8 + 4 * (mt & 1)] = u;
    }
    const float* al = av;
    const float* ar = av + dh;
    float pl[4] = {0.f, 0.f, 0.f, 0.f}, pr[4] = {0.f, 0.f, 0.f, 0.f};
    #pragma unroll
    for (int nt = 0; nt < 4; ++nt) {
        const int q = (cb * 64 + 16 * nt + n16) & (dh - 1);
        const float wl = al[q], wr_ = ar[q];
        #pragma unroll
        for (int r = 0; r < 4; ++r) { pl[r] += acc[nt][r] * wl; pr[r] += acc[nt][r] * wr_; }
    }
    #pragma unroll
    for (int r = 0; r < 4; ++r) {
        #pragma unroll
        for (int off = 1; off < 16; off <<= 1) {
            pl[r] += __shfl_xor(pl[r], off);
            pr[r] += __shfl_xor(pr[r], off);
        }
    }
    if (n16 == 0) {
        const int hbase = (dh == 64 ? cb : 0) * NN;
        #pragma unroll
        for (int r = 0; r < 4; ++r) {
            const int grow = 16 * mt + 4 * gq + r;
            atomicAdd(&slO[hbase + grow], pl[r] * LOG2E);
            atomicAdd(&srO[hbase + grow], pr[r] * LOG2E);
        }
    }
}

// ================= attention task (R8-verbatim) ====================================
template<int MT, int OUTMODE>
__device__ __forceinline__ void attn_task(
    const float* __restrict__ slv, const float* __restrict__ srv,
    const unsigned short* __restrict__ gp, const unsigned int* __restrict__ adjm32,
    float* __restrict__ out, unsigned short* __restrict__ aoH, unsigned short* __restrict__ aoL,
    int out_cols, int h, int do_elu, int ntg_total, int ib, int cb,
    float* accs_raw, float* zpf, int t)
{
    const int w = t >> 6, l = t & 63;
    const int gq = l >> 4, n16 = l & 15;
    const int i0 = ib * (MT * 16);
    const int ntg0 = cb * 4;
    const float* srh = srv + (size_t)h * NN;
    int arow[MT];
    float slr[MT];
    #pragma unroll
    for (int mt = 0; mt < MT; ++mt) {
        arow[mt] = i0 + 16 * mt + n16;
        slr[mt] = slv[(size_t)h * NN + arow[mt]];
    }

    f32x4 acc[MT][4];
    float zacc[MT];
    #pragma unroll
    for (int mt = 0; mt < MT; ++mt) {
        zacc[mt] = 0.f;
        #pragma unroll
        for (int nt = 0; nt < 4; ++nt) acc[mt][nt] = f32x4{0.f, 0.f, 0.f, 0.f};
    }

#define LOADH(bf_, sr_, am_, tile_, s_) do {                                     \
    const int tl_ = (tile_);                                                     \
    _Pragma("unroll")                                                            \
    for (int nt_ = 0; nt_ < 4; ++nt_)                                            \
        bf_[nt_] = *(const short8*)&gp[                                          \
            (size_t)((2 * tl_ + (s_)) * ntg_total + ntg0 + nt_) * 512 + l * 8];  \
    _Pragma("unroll")                                                            \
    for (int hb_ = 0; hb_ < 2; ++hb_)                                            \
        sr_[hb_] = *(const f32x4*)&srh[64 * tl_ + 32 * (s_) + 16 * hb_ + 4 * gq];\
    _Pragma("unroll")                                                            \
    for (int mt_ = 0; mt_ < MT; ++mt_)                                           \
        am_[mt_] = adjm32[((size_t)arow[mt_] * 32 + tl_) * 2 + (s_)];            \
} while (0)

#define COMPH(bf_, sr_, am_) do {                                                \
    short8 af_[MT];                                                              \
    _Pragma("unroll")                                                            \
    for (int mt_ = 0; mt_ < MT; ++mt_) {                                         \
        const unsigned am32_ = am_[mt_] >> (4 * gq);                             \
        _Pragma("unroll")                                                        \
        for (int hb_ = 0; hb_ < 2; ++hb_) {                                      \
            const f32x4 s4_ = sr_[hb_];                                          \
            _Pragma("unroll")                                                    \
            for (int c_ = 0; c_ < 4; ++c_) {                                     \
                float f_ = slr[mt_] + s4_[c_];                                   \
                f_ = fmaxf(f_, 0.2f * f_);                                       \
                float wv_ = __builtin_amdgcn_exp2f(f_);                          \
                const int msk_ = (int)(am32_ << (31 - (c_ + 16 * hb_))) >> 31;   \
                wv_ = __int_as_float(__float_as_int(wv_) & msk_);                \
                zacc[mt_] += wv_;                                                \
                af_[mt_][4 * hb_ + c_] = f2bfs(wv_);                             \
            }                                                                    \
        }                                                                        \
    }                                                                            \
    _Pragma("unroll")                                                            \
    for (int mt_ = 0; mt_ < MT; ++mt_)                                           \
        _Pragma("unroll")                                                        \
        for (int nt_ = 0; nt_ < 4; ++nt_)                                        \
            acc[mt_][nt_] = __builtin_amdgcn_mfma_f32_16x16x32_bf16(             \
                af_[mt_], bf_[nt_], acc[mt_][nt_], 0, 0, 0);                     \
} while (0)

    unsigned amA[MT], amB[MT];
    f32x4 srA[2], srB[2];
    short8 bfA[4], bfB[4];

    LOADH(bfA, srA, amA, w, 0);
    LOADH(bfB, srB, amB, w, 1);
    #pragma unroll
    for (int k = 0; k < 4; ++k) {
        const int tn = (k < 3) ? (w + 8 * (k + 1)) : (w + 8 * k);   // guarded prefetch
        COMPH(bfA, srA, amA);
        LOADH(bfA, srA, amA, tn, 0);
        COMPH(bfB, srB, amB);
        LOADH(bfB, srB, amB, tn, 1);
    }
#undef LOADH
#undef COMPH

    #pragma unroll
    for (int mt = 0; mt < MT; ++mt) {
        zacc[mt] += __shfl_xor(zacc[mt], 16);
        zacc[mt] += __shfl_xor(zacc[mt], 32);
    }
    if (l < 16) {
        #pragma unroll
        for (int mt = 0; mt < MT; ++mt) zpf[w * (MT * 16) + 16 * mt + l] = zacc[mt];
    }

    if constexpr (OUTMODE == 0) {
        #pragma unroll
        for (int nt = 0; nt < 4; ++nt)
            #pragma unroll
            for (int r = 0; r < 4; ++r)
                accs_raw[((w * 4 + nt) * 4 + r) * 65 + l] = acc[0][nt][r];
        __syncthreads();
        #pragma unroll
        for (int idx = 0; idx < 2; ++idx) {
            const int flat = w + 8 * idx;            // 0..15
            const int nt = flat >> 2, r = flat & 3;
            const int ro = 4 * gq + r;
            float z = 0.f, v = 0.f;
            #pragma unroll
            for (int jj = 0; jj < 8; ++jj) {
                z += zpf[jj * 16 + ro];
                v += accs_raw[((jj * 4 + nt) * 4 + r) * 65 + l];
            }
            float o = v / z;
            if (do_elu) o = (o > 0.f) ? o : (__builtin_amdgcn_exp2f(o * LOG2E) - 1.f);
            out[(size_t)(i0 + ro) * out_cols + cb * 64 + nt * 16 + n16] = o;
        }
    } else {
        const int mtl = w & 1, eh = (w >> 1) & 1;
        const int rowl = l & 15, colq = l >> 4;
        #pragma unroll
        for (int h2 = 0; h2 < 2; ++h2) {
            #pragma unroll
            for (int mt = 0; mt < MT; ++mt)
                #pragma unroll
                for (int ntl = 0; ntl < 2; ++ntl)
                    #pragma unroll
                    for (int r = 0; r < 4; ++r)
                        accs_raw[(((w * 2 + mt) * 2 + ntl) * 4 + r) * 65 + l] =
                            acc[mt][2 * h2 + ntl][r];
            __syncthreads();
            if (w < 4) {
                const int grow = 16 * mtl + rowl;
                float z = 0.f;
                #pragma unroll
                for (int jj = 0; jj < 8; ++jj) z += zpf[jj * 32 + grow];
                const float rz = 1.0f / z;
                unsigned short uh[4], ul[4];
                #pragma unroll
                for (int c = 0; c < 4; ++c) {
                    const int c16 = 4 * colq + c;
                    float v = 0.f;
                    #pragma unroll
                    for (int jj = 0; jj < 8; ++jj)
                        v += accs_raw[(((jj * 2 + mtl) * 2 + eh) * 4 + (rowl & 3)) * 65
                                      + (rowl >> 2) * 16 + c16];
                    float o = v * rz;
                    o = (o > 0.f) ? o : (__builtin_amdgcn_exp2f(o * LOG2E) - 1.f);  // ELU
                    const unsigned short hi = f2bfu(o);
                    uh[c] = hi;
                    ul[c] = f2bfu(o - bfu2f(hi));
                }
                const int mtg = ib * 2 + mtl;
                const int kt = 2 * cb + h2;
                const size_t off = ((size_t)mtg * 16 + kt) * 512 + l * 8 + 4 * eh;
                *(s16x4*)&aoH[off] = *(const s16x4*)uh;
                *(s16x4*)&aoL[off] = *(const s16x4*)ul;
            }
            __syncthreads();
        }
    }
}

// ================= kernels =========================================================
// prep: 848 blocks. [0,144) zero scores; [144,336) W-pack; [336,848) x-pack.
__global__ __launch_bounds__(256) void prep_k(
    float* __restrict__ zeros,
    const float* __restrict__ W1, unsigned short* __restrict__ w1H, unsigned short* __restrict__ w1L,
    const float* __restrict__ W2, unsigned short* __restrict__ w2H, unsigned short* __restrict__ w2L,
    const float* __restrict__ x, unsigned short* __restrict__ axH, unsigned short* __restrict__ axL)
{
    const int b = blockIdx.x, t = threadIdx.x, w = t >> 6, l = t & 63;
    if (b < 144) {
        zeros[b * 256 + t] = 0.f;
    } else if (b < 336) {
        wpack_task(W1, w1H, w1L, W2, w2H, w2L, (b - 144) * 4 + w, l);
    } else {
        xpack_task(x, axH, axL, (b - 336) * 4 + w, l);
    }
}

// gemm: 1D grid, cb = bid & cbmask (XCD-pinned), mt = (bid>>cbshift)*4 + w.
// do_adj: tail loop packs adjacency (64 tasks/wave, unroll 8 keeps loads in flight).
__global__ __launch_bounds__(256, 2) void gemm_k(
    const unsigned short* __restrict__ aH, const unsigned short* __restrict__ aL,
    const unsigned short* __restrict__ bH, const unsigned short* __restrict__ bL,
    const float* __restrict__ av, unsigned short* __restrict__ gpO,
    float* __restrict__ slO, float* __restrict__ srO, int dh, int NT,
    int cbmask, int cbshift,
    int do_adj, const int* __restrict__ adj, unsigned long long* __restrict__ adjm)
{
    const int t = threadIdx.x, w = t >> 6, l = t & 63;
    const int bid = blockIdx.x;
    const int cb = bid & cbmask;
    const int mt = (bid >> cbshift) * 4 + w;
    gemm_wave(aH, aL, bH, bL, av, gpO, slO, srO, dh, NT, mt, cb, l);
    if (do_adj) {
        const int gwave = bid * 4 + w;          // 0..1023
        #pragma unroll 8
        for (int i = 0; i < 64; ++i)
            adj_task(adj, adjm, gwave + 1024 * i, l);
    }
}

// attn: 1D grid, cb = bid & cbmask (XCD-pinned), ib = bid >> cbshift.
template<int MT, int OUTMODE>
__global__ __launch_bounds__(512, 4) void attn_k(
    const float* __restrict__ slv, const float* __restrict__ srv,
    const unsigned short* __restrict__ gp, const unsigned int* __restrict__ adjm32,
    float* __restrict__ out, unsigned short* __restrict__ aoH, unsigned short* __restrict__ aoL,
    int out_cols, int hsel, int do_elu, int ntg_total, int cbmask, int cbshift)
{
    __shared__ float accs_raw[8320];
    __shared__ float zpf[256];
    const int bid = blockIdx.x;
    const int cb = bid & cbmask;
    const int ib = bid >> cbshift;
    const int h = (hsel < 0) ? cb : hsel;
    attn_task<MT, OUTMODE>(slv, srv, gp, adjm32, out, aoH, aoL, out_cols, h, do_elu,
                           ntg_total, ib, cb, accs_raw, zpf, threadIdx.x);
}

extern "C" void kernel_launch(void* const* d_in, const int* in_sizes, int n_in,
                              void* d_out, int out_size, void* d_ws, size_t ws_size,
                              hipStream_t stream)
{
    const float* x   = (const float*)d_in[0];   // 2048 x 512
    const int*   adj = (const int*)  d_in[1];   // 2048 x 2048
    const float* W1  = (const float*)d_in[2];   // 512 x 512
    const float* a1  = (const float*)d_in[3];   // 128
    const float* W2  = (const float*)d_in[4];   // 512 x 256
    const float* a2  = (const float*)d_in[5];   // 512
    float* outp = (float*)d_out;                // 2048 x 256

    float* sl1 = (float*)d_ws;                  // 8*2048 (head-major)
    float* sr1 = sl1 + 8 * 2048;
    float* sl2 = sr1 + 8 * 2048;                // 2048
    float* sr2 = sl2 + 2048;
    unsigned long long* adjm = (unsigned long long*)(sr2 + 2048);   // 65536 u64
    unsigned short* gp1 = (unsigned short*)(adjm + 65536);          // 2048 frags
    unsigned short* gp2 = gp1 + 2048 * 512;     // 1024 frags
    unsigned short* axH = gp2 + 1024 * 512;
    unsigned short* axL = axH + 2048 * 512;
    unsigned short* ahH = axL + 2048 * 512;
    unsigned short* ahL = ahH + 2048 * 512;
    unsigned short* w1H = ahL + 2048 * 512;
    unsigned short* w1L = w1H + 512 * 512;
    unsigned short* w2H = w1L + 512 * 512;
    unsigned short* w2L = w2H + 256 * 512;

    // P0: zero scores + pack W1/W2 + pack x  (adj-pack moved into gemm1)
    prep_k<<<dim3(848), 256, 0, stream>>>(sl1, W1, w1H, w1L, W2, w2H, w2L, x, axH, axL);

    // L1 GEMM (+ PV-frags + scores + adj-pack tail); cb = bid&7 XCD-pinned
    gemm_k<<<dim3(256), 256, 0, stream>>>(axH, axL, w1H, w1L, a1, gp1, sl1, sr1,
                                          64, 32, 7, 3, 1, adj, adjm);
    // L1 attention (MT=2, emits split-bf16 A-frags for L2, ELU)
    attn_k<2, 1><<<dim3(512), 512, 0, stream>>>(sl1, sr1, gp1, (const unsigned int*)adjm,
                                                nullptr, ahH, ahL, 512, -1, 1, 32, 7, 3);
    // L2 GEMM
    gemm_k<<<dim3(128), 256, 0, stream>>>(ahH, ahL, w2H, w2L, a2, gp2, sl2, sr2,
                                          256, 16, 3, 2, 0, nullptr, nullptr);
    // L2 attention (MT=1, fp32 out)
    attn_k<1, 0><<<dim3(512), 512, 0, stream>>>(sl2, sr2, gp2, (const unsigned int*)adjm,
                                                outp, nullptr, nullptr, 256, 0, 0, 16, 3, 2);
}

// Round 12
// 59.267 us; speedup vs baseline: 8.1983x; 1.1916x over previous
//
#include <hip/hip_runtime.h>
#include <hip/hip_bf16.h>
#include <math.h>

#define NN 2048
#define LOG2E 1.4426950408889634f

typedef __attribute__((ext_vector_type(8))) short short8;
typedef __attribute__((ext_vector_type(4))) short s16x4;
typedef __attribute__((ext_vector_type(4))) float f32x4;

__device__ inline unsigned short f2bfu(float f) {
    __hip_bfloat16 h = __float2bfloat16(f);
    return *reinterpret_cast<const unsigned short*>(&h);
}
__device__ inline short f2bfs(float f) {
    __hip_bfloat16 h = __float2bfloat16(f);
    return *reinterpret_cast<const short*>(&h);
}
__device__ inline float bfu2f(unsigned short u) {
    return __uint_as_float(((unsigned int)u) << 16);
}

// ================= prep sub-tasks ==================================================
__device__ __forceinline__ void adj_task(
    const int* __restrict__ adj, unsigned long long* __restrict__ adjm, int task, int l)
{
    const int row = task >> 5, ch = task & 31;
    const int v = adj[(size_t)row * NN + ch * 64 + l];
    const unsigned long long bm = __ballot(v != 0);
    if (l == 0) adjm[task] = bm;
}

__device__ __forceinline__ void xpack_task(
    const float* __restrict__ x, unsigned short* __restrict__ axH,
    unsigned short* __restrict__ axL, int f, int l)
{
    const int gq = l >> 4, n16 = l & 15;
    const int mt = f >> 4, kt = f & 15;
    const int row = mt * 16 + n16;
    const int k0 = kt * 32 + 4 * gq;
    unsigned short uh[8], ul[8];
    #pragma unroll
    for (int eh = 0; eh < 2; ++eh) {
        const float4 v4 = *(const float4*)&x[(size_t)row * 512 + k0 + 16 * eh];
        const float vv[4] = {v4.x, v4.y, v4.z, v4.w};
        #pragma unroll
        for (int c = 0; c < 4; ++c) {
            const float v = vv[c];
            const unsigned short hi = f2bfu(v);
            uh[4 * eh + c] = hi;
            ul[4 * eh + c] = f2bfu(v - bfu2f(hi));
        }
    }
    *(short8*)&axH[(size_t)f * 512 + l * 8] = *(const short8*)uh;
    *(short8*)&axL[(size_t)f * 512 + l * 8] = *(const short8*)ul;
}

__device__ __forceinline__ void wpack_task(
    const float* __restrict__ W1, unsigned short* __restrict__ w1H, unsigned short* __restrict__ w1L,
    const float* __restrict__ W2, unsigned short* __restrict__ w2H, unsigned short* __restrict__ w2L,
    int f0, int l)
{
    const int gq = l >> 4, n16 = l & 15;
    int f = f0;
    const float* B; unsigned short *bH, *bL; int N;
    if (f < 512) { B = W1; bH = w1H; bL = w1L; N = 512; }
    else         { B = W2; bH = w2H; bL = w2L; N = 256; f -= 512; }
    const int nt = f >> 4, kt = f & 15;
    const int col = nt * 16 + n16;
    unsigned short uh[8], ul[8];
    #pragma unroll
    for (int e = 0; e < 8; ++e) {
        const int k = kt * 32 + 4 * gq + (e & 3) + 16 * (e >> 2);
        const float v = B[(size_t)k * N + col];
        const unsigned short hi = f2bfu(v);
        uh[e] = hi;
        ul[e] = f2bfu(v - bfu2f(hi));
    }
    *(short8*)&bH[(size_t)f * 512 + l * 8] = *(const short8*)uh;
    *(short8*)&bL[(size_t)f * 512 + l * 8] = *(const short8*)ul;
}

// ================= per-wave split-bf16 GEMM + fused epilogue =======================
__device__ __forceinline__ void gemm_wave(
    const unsigned short* __restrict__ aH, const unsigned short* __restrict__ aL,
    const unsigned short* __restrict__ bH, const unsigned short* __restrict__ bL,
    const float* __restrict__ av, unsigned short* __restrict__ gpO,
    float* __restrict__ slO, float* __restrict__ srO,
    int dh, int NT, int mt, int cb, int l)
{
    const int gq = l >> 4, n16 = l & 15;
    const int nt0 = cb * 4;
    const size_t abase = (size_t)mt * 16 * 512 + l * 8;

    f32x4 acc[4];
    #pragma unroll
    for (int nt = 0; nt < 4; ++nt) acc[nt] = f32x4{0.f, 0.f, 0.f, 0.f};

#define GGL(aH_v, aL_v, bH_v, bL_v, kt_) do {                                    \
    const int kk_ = (kt_);                                                       \
    aH_v = *(const short8*)&aH[abase + (size_t)kk_ * 512];                       \
    aL_v = *(const short8*)&aL[abase + (size_t)kk_ * 512];                       \
    _Pragma("unroll")                                                            \
    for (int nt_ = 0; nt_ < 4; ++nt_) {                                          \
        const size_t bo_ = ((size_t)(nt0 + nt_) * 16 + kk_) * 512 + l * 8;       \
        bH_v[nt_] = *(const short8*)&bH[bo_];                                    \
        bL_v[nt_] = *(const short8*)&bL[bo_];                                    \
    }                                                                            \
} while (0)

#define GGC(aH_v, aL_v, bH_v, bL_v) do {                                         \
    _Pragma("unroll")                                                            \
    for (int nt_ = 0; nt_ < 4; ++nt_) {                                          \
        acc[nt_] = __builtin_amdgcn_mfma_f32_16x16x32_bf16(aH_v, bH_v[nt_], acc[nt_], 0, 0, 0); \
        acc[nt_] = __builtin_amdgcn_mfma_f32_16x16x32_bf16(aH_v, bL_v[nt_], acc[nt_], 0, 0, 0); \
        acc[nt_] = __builtin_amdgcn_mfma_f32_16x16x32_bf16(aL_v, bH_v[nt_], acc[nt_], 0, 0, 0); \
    }                                                                            \
} while (0)

    short8 aHa, aLa, bHa[4], bLa[4], aHb, aLb, bHb[4], bLb[4];
    GGL(aHa, aLa, bHa, bLa, 0);
    GGL(aHb, aLb, bHb, bLb, 1);
    for (int kt = 0; kt < 16; kt += 2) {
        GGC(aHa, aLa, bHa, bLa);
        if (kt + 2 < 16) GGL(aHa, aLa, bHa, bLa, kt + 2);
        GGC(aHb, aLb, bHb, bLb);
        if (kt + 3 < 16) GGL(aHb, aLb, bHb, bLb, kt + 3);
    }
#undef GGL
#undef GGC

    #pragma unroll
    for (int nt = 0; nt < 4; ++nt) {
        s16x4 u;
        #pragma unroll
        for (int c = 0; c < 4; ++c) u[c] = (short)f2bfu(acc[nt][c]);
        const int f = (mt >> 1) * NT + (nt0 + nt);
        *(s16x4*)&gpO[(size_t)f * 512 + l * 8 + 4 * (mt & 1)] = u;
    }
    const float* al = av;
    const float* ar = av + dh;
    float pl[4] = {0.f, 0.f, 0.f, 0.f}, pr[4] = {0.f, 0.f, 0.f, 0.f};
    #pragma unroll
    for (int nt = 0; nt < 4; ++nt) {
        const int q = (cb * 64 + 16 * nt + n16) & (dh - 1);
        const float wl = al[q], wr_ = ar[q];
        #pragma unroll
        for (int r = 0; r < 4; ++r) { pl[r] += acc[nt][r] * wl; pr[r] += acc[nt][r] * wr_; }
    }
    #pragma unroll
    for (int r = 0; r < 4; ++r) {
        #pragma unroll
        for (int off = 1; off < 16; off <<= 1) {
            pl[r] += __shfl_xor(pl[r], off);
            pr[r] += __shfl_xor(pr[r], off);
        }
    }
    if (n16 == 0) {
        const int hbase = (dh == 64 ? cb : 0) * NN;
        #pragma unroll
        for (int r = 0; r < 4; ++r) {
            const int grow = 16 * mt + 4 * gq + r;
            atomicAdd(&slO[hbase + grow], pl[r] * LOG2E);
            atomicAdd(&srO[hbase + grow], pr[r] * LOG2E);
        }
    }
}

// ================= attention task (R8-verbatim) ====================================
template<int MT, int OUTMODE>
__device__ __forceinline__ void attn_task(
    const float* __restrict__ slv, const float* __restrict__ srv,
    const unsigned short* __restrict__ gp, const unsigned int* __restrict__ adjm32,
    float* __restrict__ out, unsigned short* __restrict__ aoH, unsigned short* __restrict__ aoL,
    int out_cols, int h, int do_elu, int ntg_total, int ib, int cb,
    float* accs_raw, float* zpf, int t)
{
    const int w = t >> 6, l = t & 63;
    const int gq = l >> 4, n16 = l & 15;
    const int i0 = ib * (MT * 16);
    const int ntg0 = cb * 4;
    const float* srh = srv + (size_t)h * NN;
    int arow[MT];
    float slr[MT];
    #pragma unroll
    for (int mt = 0; mt < MT; ++mt) {
        arow[mt] = i0 + 16 * mt + n16;
        slr[mt] = slv[(size_t)h * NN + arow[mt]];
    }

    f32x4 acc[MT][4];
    float zacc[MT];
    #pragma unroll
    for (int mt = 0; mt < MT; ++mt) {
        zacc[mt] = 0.f;
        #pragma unroll
        for (int nt = 0; nt < 4; ++nt) acc[mt][nt] = f32x4{0.f, 0.f, 0.f, 0.f};
    }

#define LOADH(bf_, sr_, am_, tile_, s_) do {                                     \
    const int tl_ = (tile_);                                                     \
    _Pragma("unroll")                                                            \
    for (int nt_ = 0; nt_ < 4; ++nt_)                                            \
        bf_[nt_] = *(const short8*)&gp[                                          \
            (size_t)((2 * tl_ + (s_)) * ntg_total + ntg0 + nt_) * 512 + l * 8];  \
    _Pragma("unroll")                                                            \
    for (int hb_ = 0; hb_ < 2; ++hb_)                                            \
        sr_[hb_] = *(const f32x4*)&srh[64 * tl_ + 32 * (s_) + 16 * hb_ + 4 * gq];\
    _Pragma("unroll")                                                            \
    for (int mt_ = 0; mt_ < MT; ++mt_)                                           \
        am_[mt_] = adjm32[((size_t)arow[mt_] * 32 + tl_) * 2 + (s_)];            \
} while (0)

#define COMPH(bf_, sr_, am_) do {                                                \
    short8 af_[MT];                                                              \
    _Pragma("unroll")                                                            \
    for (int mt_ = 0; mt_ < MT; ++mt_) {                                         \
        const unsigned am32_ = am_[mt_] >> (4 * gq);                             \
        _Pragma("unroll")                                                        \
        for (int hb_ = 0; hb_ < 2; ++hb_) {                                      \
            const f32x4 s4_ = sr_[hb_];                                          \
            _Pragma("unroll")                                                    \
            for (int c_ = 0; c_ < 4; ++c_) {                                     \
                float f_ = slr[mt_] + s4_[c_];                                   \
                f_ = fmaxf(f_, 0.2f * f_);                                       \
                float wv_ = __builtin_amdgcn_exp2f(f_);                          \
                const int msk_ = (int)(am32_ << (31 - (c_ + 16 * hb_))) >> 31;   \
                wv_ = __int_as_float(__float_as_int(wv_) & msk_);                \
                zacc[mt_] += wv_;                                                \
                af_[mt_][4 * hb_ + c_] = f2bfs(wv_);                             \
            }                                                                    \
        }                                                                        \
    }                                                                            \
    _Pragma("unroll")                                                            \
    for (int mt_ = 0; mt_ < MT; ++mt_)                                           \
        _Pragma("unroll")                                                        \
        for (int nt_ = 0; nt_ < 4; ++nt_)                                        \
            acc[mt_][nt_] = __builtin_amdgcn_mfma_f32_16x16x32_bf16(             \
                af_[mt_], bf_[nt_], acc[mt_][nt_], 0, 0, 0);                     \
} while (0)

    unsigned amA[MT], amB[MT];
    f32x4 srA[2], srB[2];
    short8 bfA[4], bfB[4];

    LOADH(bfA, srA, amA, w, 0);
    LOADH(bfB, srB, amB, w, 1);
    #pragma unroll
    for (int k = 0; k < 4; ++k) {
        const int tn = (k < 3) ? (w + 8 * (k + 1)) : (w + 8 * k);   // guarded prefetch
        COMPH(bfA, srA, amA);
        LOADH(bfA, srA, amA, tn, 0);
        COMPH(bfB, srB, amB);
        LOADH(bfB, srB, amB, tn, 1);
    }
#undef LOADH
#undef COMPH

    #pragma unroll
    for (int mt = 0; mt < MT; ++mt) {
        zacc[mt] += __shfl_xor(zacc[mt], 16);
        zacc[mt] += __shfl_xor(zacc[mt], 32);
    }
    if (l < 16) {
        #pragma unroll
        for (int mt = 0; mt < MT; ++mt) zpf[w * (MT * 16) + 16 * mt + l] = zacc[mt];
    }

    if constexpr (OUTMODE == 0) {
        #pragma unroll
        for (int nt = 0; nt < 4; ++nt)
            #pragma unroll
            for (int r = 0; r < 4; ++r)
                accs_raw[((w * 4 + nt) * 4 + r) * 65 + l] = acc[0][nt][r];
        __syncthreads();
        #pragma unroll
        for (int idx = 0; idx < 2; ++idx) {
            const int flat = w + 8 * idx;            // 0..15
            const int nt = flat >> 2, r = flat & 3;
            const int ro = 4 * gq + r;
            float z = 0.f, v = 0.f;
            #pragma unroll
            for (int jj = 0; jj < 8; ++jj) {
                z += zpf[jj * 16 + ro];
                v += accs_raw[((jj * 4 + nt) * 4 + r) * 65 + l];
            }
            float o = v / z;
            if (do_elu) o = (o > 0.f) ? o : (__builtin_amdgcn_exp2f(o * LOG2E) - 1.f);
            out[(size_t)(i0 + ro) * out_cols + cb * 64 + nt * 16 + n16] = o;
        }
    } else {
        const int mtl = w & 1, eh = (w >> 1) & 1;
        const int rowl = l & 15, colq = l >> 4;
        #pragma unroll
        for (int h2 = 0; h2 < 2; ++h2) {
            #pragma unroll
            for (int mt = 0; mt < MT; ++mt)
                #pragma unroll
                for (int ntl = 0; ntl < 2; ++ntl)
                    #pragma unroll
                    for (int r = 0; r < 4; ++r)
                        accs_raw[(((w * 2 + mt) * 2 + ntl) * 4 + r) * 65 + l] =
                            acc[mt][2 * h2 + ntl][r];
            __syncthreads();
            if (w < 4) {
                const int grow = 16 * mtl + rowl;
                float z = 0.f;
                #pragma unroll
                for (int jj = 0; jj < 8; ++jj) z += zpf[jj * 32 + grow];
                const float rz = 1.0f / z;
                unsigned short uh[4], ul[4];
                #pragma unroll
                for (int c = 0; c < 4; ++c) {
                    const int c16 = 4 * colq + c;
                    float v = 0.f;
                    #pragma unroll
                    for (int jj = 0; jj < 8; ++jj)
                        v += accs_raw[(((jj * 2 + mtl) * 2 + eh) * 4 + (rowl & 3)) * 65
                                      + (rowl >> 2) * 16 + c16];
                    float o = v * rz;
                    o = (o > 0.f) ? o : (__builtin_amdgcn_exp2f(o * LOG2E) - 1.f);  // ELU
                    const unsigned short hi = f2bfu(o);
                    uh[c] = hi;
                    ul[c] = f2bfu(o - bfu2f(hi));
                }
                const int mtg = ib * 2 + mtl;
                const int kt = 2 * cb + h2;
                const size_t off = ((size_t)mtg * 16 + kt) * 512 + l * 8 + 4 * eh;
                *(s16x4*)&aoH[off] = *(const s16x4*)uh;
                *(s16x4*)&aoL[off] = *(const s16x4*)ul;
            }
            __syncthreads();
        }
    }
}

// ================= kernels =========================================================
// prep: 848 blocks. [0,144) zero scores; [144,336) W-pack; [336,848) x-pack.
__global__ __launch_bounds__(256) void prep_k(
    float* __restrict__ zeros,
    const float* __restrict__ W1, unsigned short* __restrict__ w1H, unsigned short* __restrict__ w1L,
    const float* __restrict__ W2, unsigned short* __restrict__ w2H, unsigned short* __restrict__ w2L,
    const float* __restrict__ x, unsigned short* __restrict__ axH, unsigned short* __restrict__ axL)
{
    const int b = blockIdx.x, t = threadIdx.x, w = t >> 6, l = t & 63;
    if (b < 144) {
        zeros[b * 256 + t] = 0.f;
    } else if (b < 336) {
        wpack_task(W1, w1H, w1L, W2, w2H, w2L, (b - 144) * 4 + w, l);
    } else {
        xpack_task(x, axH, axL, (b - 336) * 4 + w, l);
    }
}

// gemm: bid < ngemm -> GEMM task (cb = bid & cbmask, mt = (bid>>cbshift)*4 + w);
//       bid >= ngemm -> adjacency-pack block (CONCURRENT with gemm blocks: pure
//       memory work on the CU's second block slot; 16 tasks/wave, unroll 4).
__global__ __launch_bounds__(256, 2) void gemm_k(
    const unsigned short* __restrict__ aH, const unsigned short* __restrict__ aL,
    const unsigned short* __restrict__ bH, const unsigned short* __restrict__ bL,
    const float* __restrict__ av, unsigned short* __restrict__ gpO,
    float* __restrict__ slO, float* __restrict__ srO, int dh, int NT,
    int cbmask, int cbshift, int ngemm,
    const int* __restrict__ adj, unsigned long long* __restrict__ adjm)
{
    const int t = threadIdx.x, w = t >> 6, l = t & 63;
    const int bid = blockIdx.x;
    if (bid < ngemm) {
        const int cb = bid & cbmask;
        const int mt = (bid >> cbshift) * 4 + w;
        gemm_wave(aH, aL, bH, bL, av, gpO, slO, srO, dh, NT, mt, cb, l);
    } else {
        const int ab = bid - ngemm;             // 0..1023
        const int gwave = ab * 4 + w;           // 0..4095
        #pragma unroll 4
        for (int i = 0; i < 16; ++i)
            adj_task(adj, adjm, gwave + 4096 * i, l);
    }
}

// attn: 1D grid, cb = bid & cbmask (XCD-pinned), ib = bid >> cbshift.
template<int MT, int OUTMODE>
__global__ __launch_bounds__(512, 4) void attn_k(
    const float* __restrict__ slv, const float* __restrict__ srv,
    const unsigned short* __restrict__ gp, const unsigned int* __restrict__ adjm32,
    float* __restrict__ out, unsigned short* __restrict__ aoH, unsigned short* __restrict__ aoL,
    int out_cols, int hsel, int do_elu, int ntg_total, int cbmask, int cbshift)
{
    __shared__ float accs_raw[8320];
    __shared__ float zpf[256];
    const int bid = blockIdx.x;
    const int cb = bid & cbmask;
    const int ib = bid >> cbshift;
    const int h = (hsel < 0) ? cb : hsel;
    attn_task<MT, OUTMODE>(slv, srv, gp, adjm32, out, aoH, aoL, out_cols, h, do_elu,
                           ntg_total, ib, cb, accs_raw, zpf, threadIdx.x);
}

extern "C" void kernel_launch(void* const* d_in, const int* in_sizes, int n_in,
                              void* d_out, int out_size, void* d_ws, size_t ws_size,
                              hipStream_t stream)
{
    const float* x   = (const float*)d_in[0];   // 2048 x 512
    const int*   adj = (const int*)  d_in[1];   // 2048 x 2048
    const float* W1  = (const float*)d_in[2];   // 512 x 512
    const float* a1  = (const float*)d_in[3];   // 128
    const float* W2  = (const float*)d_in[4];   // 512 x 256
    const float* a2  = (const float*)d_in[5];   // 512
    float* outp = (float*)d_out;                // 2048 x 256

    float* sl1 = (float*)d_ws;                  // 8*2048 (head-major)
    float* sr1 = sl1 + 8 * 2048;
    float* sl2 = sr1 + 8 * 2048;                // 2048
    float* sr2 = sl2 + 2048;
    unsigned long long* adjm = (unsigned long long*)(sr2 + 2048);   // 65536 u64
    unsigned short* gp1 = (unsigned short*)(adjm + 65536);          // 2048 frags
    unsigned short* gp2 = gp1 + 2048 * 512;     // 1024 frags
    unsigned short* axH = gp2 + 1024 * 512;
    unsigned short* axL = axH + 2048 * 512;
    unsigned short* ahH = axL + 2048 * 512;
    unsigned short* ahL = ahH + 2048 * 512;
    unsigned short* w1H = ahL + 2048 * 512;
    unsigned short* w1L = w1H + 512 * 512;
    unsigned short* w2H = w1L + 512 * 512;
    unsigned short* w2L = w2H + 256 * 512;

    // P0: zero scores + pack W1/W2 + pack x
    prep_k<<<dim3(848), 256, 0, stream>>>(sl1, W1, w1H, w1L, W2, w2H, w2L, x, axH, axL);

    // L1 GEMM (256 gemm blocks) + 1024 concurrent adj-pack blocks
    gemm_k<<<dim3(1280), 256, 0, stream>>>(axH, axL, w1H, w1L, a1, gp1, sl1, sr1,
                                           64, 32, 7, 3, 256, adj, adjm);
    // L1 attention (MT=2, emits split-bf16 A-frags for L2, ELU); cb XCD-pinned
    attn_k<2, 1><<<dim3(512), 512, 0, stream>>>(sl1, sr1, gp1, (const unsigned int*)adjm,
                                                nullptr, ahH, ahL, 512, -1, 1, 32, 7, 3);
    // L2 GEMM (no adj blocks)
    gemm_k<<<dim3(128), 256, 0, stream>>>(ahH, ahL, w2H, w2L, a2, gp2, sl2, sr2,
                                          256, 16, 3, 2, 128, nullptr, nullptr);
    // L2 attention (MT=1, fp32 out)
    attn_k<1, 0><<<dim3(512), 512, 0, stream>>>(sl2, sr2, gp2, (const unsigned int*)adjm,
                                                outp, nullptr, nullptr, 256, 0, 0, 16, 3, 2);
}